// Round 1
// baseline (798.083 us; speedup 1.0000x reference)
//
#include <hip/hip_runtime.h>
#include <stdint.h>

typedef _Float16 h16;
typedef __attribute__((ext_vector_type(8))) _Float16 f16x8;
typedef __attribute__((ext_vector_type(4))) float f32x4;

// Problem constants
// B=8, T=2048, D=1024, NODES=1024
// ws layout (bytes):
//   Xh  @ 0         : 16384*1024*2 = 33554432
//   Wt  @ 33554432  : 3*1024*1024*2 = 6291456   (Wq^T,Wk^T,Wv^T fp16, [n][d])
//   Vt  @ 39845888  : 8*1024*2048*2 = 33554432  (V transposed [b][n][t])
//   S   @ 73400320  : 2048*2048*4   = 16777216  (per-batch scores fp32)
//   P   @ 90177536  : 2048*2048*2   = 8388608   (per-batch probs fp16)
// total 98566144 (~94 MiB)
// Q,K fp16 live inside d_out: per-batch chunk of 4Mi halves = [Q_b | K_b];
// batch b's final fp32 output exactly overwrites [Q_b|K_b] after they are consumed.

// ---------------- convert X fp32 -> fp16 ----------------
__global__ __launch_bounds__(256) void k_convX(const float* __restrict__ X,
                                               h16* __restrict__ Xh) {
    size_t i = ((size_t)blockIdx.x * 256 + threadIdx.x) * 8;
    f32x4 a = *(const f32x4*)(X + i);
    f32x4 b = *(const f32x4*)(X + i + 4);
    f16x8 o;
    o[0] = (h16)a[0]; o[1] = (h16)a[1]; o[2] = (h16)a[2]; o[3] = (h16)a[3];
    o[4] = (h16)b[0]; o[5] = (h16)b[1]; o[6] = (h16)b[2]; o[7] = (h16)b[3];
    *(f16x8*)(Xh + i) = o;
}

// ---------------- transpose+convert W [d][n] fp32 -> Wt [n][d] fp16 ----------------
__global__ __launch_bounds__(256) void k_convW(const float* __restrict__ W0,
                                               const float* __restrict__ W1,
                                               const float* __restrict__ W2,
                                               h16* __restrict__ Wt) {
    __shared__ h16 LT[64 * 72];  // [n_local][d_local], pad to 72 (row stride 144B, 16B-mult)
    int which = blockIdx.x >> 8;
    int tile  = blockIdx.x & 255;
    int d0 = (tile >> 4) * 64, n0 = (tile & 15) * 64;
    const float* W = (which == 0) ? W0 : ((which == 1) ? W1 : W2);
    h16* dst = Wt + (size_t)which * (1024 * 1024);
    int t = threadIdx.x;
#pragma unroll
    for (int p = 0; p < 4; ++p) {
        int c = t + p * 256;          // 0..1023 over 64x64 tile in float4 chunks
        int r = c >> 4;               // d row 0..63
        int cf = (c & 15) * 4;        // n col
        f32x4 v = *(const f32x4*)&W[(size_t)(d0 + r) * 1024 + n0 + cf];
#pragma unroll
        for (int e = 0; e < 4; ++e) LT[(cf + e) * 72 + r] = (h16)v[e];
    }
    __syncthreads();
#pragma unroll
    for (int p = 0; p < 2; ++p) {
        int q = t + p * 256;          // 0..511
        int nl = q >> 3;              // n_local 0..63
        int dc = (q & 7) * 8;         // d chunk
        f16x8 v = *(f16x8*)&LT[nl * 72 + dc];
        *(f16x8*)&dst[(size_t)(n0 + nl) * 1024 + d0 + dc] = v;
    }
}

// ---------------- shared 128x128 GEMM core (A row-major, B^T row-major) ----------------
// block = 256 threads = 4 waves (2x2 of 64x64); BK=32; mfma_f32_16x16x32_f16
__device__ __forceinline__ void gemm_tile(const h16* __restrict__ A,
                                          const h16* __restrict__ Bt,
                                          int K, int lda, int ldb,
                                          int rowBase, int colBase,
                                          h16* lA, h16* lB, f32x4 acc[4][4]) {
    const int t = threadIdx.x;
    const int lane = t & 63, wave = t >> 6;
    const int wr = wave >> 1, wc = wave & 1;
    const int fr = lane & 15, fk = (lane >> 4) * 8;

    const int c0 = t, c1 = t + 256;
    const int r0 = c0 >> 2, k00 = (c0 & 3) * 8;
    const int r1 = c1 >> 2, k01 = (c1 & 3) * 8;
    const h16* Ap0 = A + (size_t)(rowBase + r0) * lda + k00;
    const h16* Ap1 = A + (size_t)(rowBase + r1) * lda + k01;
    const h16* Bp0 = Bt + (size_t)(colBase + r0) * ldb + k00;
    const h16* Bp1 = Bt + (size_t)(colBase + r1) * ldb + k01;
    h16* sA0 = lA + c0 * 8; h16* sA1 = lA + c1 * 8;
    h16* sB0 = lB + c0 * 8; h16* sB1 = lB + c1 * 8;

    for (int kt = 0; kt < K; kt += 32) {
        *(f16x8*)sA0 = *(const f16x8*)(Ap0 + kt);
        *(f16x8*)sA1 = *(const f16x8*)(Ap1 + kt);
        *(f16x8*)sB0 = *(const f16x8*)(Bp0 + kt);
        *(f16x8*)sB1 = *(const f16x8*)(Bp1 + kt);
        __syncthreads();
        f16x8 af[4], bf[4];
#pragma unroll
        for (int m = 0; m < 4; ++m)
            af[m] = *(const f16x8*)&lA[(wr * 64 + m * 16 + fr) * 32 + fk];
#pragma unroll
        for (int n = 0; n < 4; ++n)
            bf[n] = *(const f16x8*)&lB[(wc * 64 + n * 16 + fr) * 32 + fk];
#pragma unroll
        for (int m = 0; m < 4; ++m)
#pragma unroll
            for (int n = 0; n < 4; ++n)
                acc[m][n] = __builtin_amdgcn_mfma_f32_16x16x32_f16(af[m], bf[n], acc[m][n], 0, 0, 0);
        __syncthreads();
    }
}

// ---------------- fused QKV projection GEMM ----------------
// C[16384 x 3072] = Xh @ [Wq|Wk|Wv]; Q,K -> d_out interleaved fp16; V -> Vt transposed
__global__ __launch_bounds__(256) void k_gemm_qkv(const h16* __restrict__ Xh,
                                                  const h16* __restrict__ Wt,
                                                  h16* __restrict__ qk,
                                                  h16* __restrict__ vt) {
    __shared__ char smem[34816];  // max(16 KiB staging, 128*136*2 transpose)
    h16* lA = (h16*)smem;
    h16* lB = (h16*)(smem + 8192);

    int bid = blockIdx.x;
    int nt = bid % 24, mt = bid / 24;
    int rowBase = mt * 128, colBaseF = nt * 128;
    int which = colBaseF >> 10;     // 0=Q 1=K 2=V
    int nc0 = colBaseF & 1023;
    const h16* Bt = Wt + (size_t)which * (1024 * 1024);

    f32x4 acc[4][4];
#pragma unroll
    for (int m = 0; m < 4; ++m)
#pragma unroll
        for (int n = 0; n < 4; ++n) acc[m][n] = (f32x4){0.f, 0.f, 0.f, 0.f};

    gemm_tile(Xh, Bt, 1024, 1024, 1024, rowBase, nc0, lA, lB, acc);

    const int t = threadIdx.x;
    const int lane = t & 63, wave = t >> 6;
    const int wr = wave >> 1, wc = wave & 1;
    const int fr = lane & 15, fj = (lane >> 4) * 4;
    const int b = rowBase >> 11;        // batch
    const int tloc = rowBase & 2047;    // row within batch

    if (which < 2) {
        h16* dst = qk + (size_t)b * 4194304 + (which == 1 ? 2097152u : 0u);
#pragma unroll
        for (int m = 0; m < 4; ++m)
#pragma unroll
            for (int n = 0; n < 4; ++n) {
                int cc = nc0 + wc * 64 + n * 16 + fr;
#pragma unroll
                for (int j = 0; j < 4; ++j) {
                    int rr = tloc + wr * 64 + m * 16 + fj + j;
                    dst[(size_t)rr * 1024 + cc] = (h16)acc[m][n][j];
                }
            }
    } else {
        // transpose epilogue through LDS: write Vt[b][n][t]
        h16* LTm = (h16*)smem;  // [128 n][136] (pad 8)
#pragma unroll
        for (int m = 0; m < 4; ++m)
#pragma unroll
            for (int n = 0; n < 4; ++n) {
                int cloc = wc * 64 + n * 16 + fr;
#pragma unroll
                for (int j = 0; j < 4; ++j) {
                    int rloc = wr * 64 + m * 16 + fj + j;
                    LTm[cloc * 136 + rloc] = (h16)acc[m][n][j];
                }
            }
        __syncthreads();
#pragma unroll
        for (int p = 0; p < 8; ++p) {
            int q = t + p * 256;          // 0..2047 chunks
            int nl = q >> 4;              // n_local 0..127
            int tc = (q & 15) * 8;        // t chunk
            f16x8 v = *(f16x8*)&LTm[nl * 136 + tc];
            *(f16x8*)&vt[(size_t)b * 2097152 + (size_t)(nc0 + nl) * 2048 + tloc + tc] = v;
        }
    }
}

// ---------------- generic fp32-output GEMM (scores and out) ----------------
__global__ __launch_bounds__(256) void k_gemm_f32(const h16* __restrict__ A,
                                                  const h16* __restrict__ Bt,
                                                  float* __restrict__ C,
                                                  int lda, int ldb, int ldc,
                                                  int K, int ntiles) {
    __shared__ char smem[16384];
    h16* lA = (h16*)smem;
    h16* lB = (h16*)(smem + 8192);

    int nt = blockIdx.x % ntiles, mt = blockIdx.x / ntiles;
    int rowBase = mt * 128, colBase = nt * 128;

    f32x4 acc[4][4];
#pragma unroll
    for (int m = 0; m < 4; ++m)
#pragma unroll
        for (int n = 0; n < 4; ++n) acc[m][n] = (f32x4){0.f, 0.f, 0.f, 0.f};

    gemm_tile(A, Bt, K, lda, ldb, rowBase, colBase, lA, lB, acc);

    const int t = threadIdx.x;
    const int lane = t & 63, wave = t >> 6;
    const int wr = wave >> 1, wc = wave & 1;
    const int fr = lane & 15, fj = (lane >> 4) * 4;
#pragma unroll
    for (int m = 0; m < 4; ++m)
#pragma unroll
        for (int n = 0; n < 4; ++n) {
            int cc = colBase + wc * 64 + n * 16 + fr;
#pragma unroll
            for (int j = 0; j < 4; ++j) {
                int rr = rowBase + wr * 64 + m * 16 + fj + j;
                C[(size_t)rr * ldc + cc] = acc[m][n][j];
            }
        }
}

// ---------------- row softmax: S fp32 [2048][2048] -> P fp16 ----------------
__global__ __launch_bounds__(256) void k_softmax(const float* __restrict__ S,
                                                 h16* __restrict__ P) {
    int row = blockIdx.x, t = threadIdx.x;
    const float* sr = S + (size_t)row * 2048 + t * 8;
    f32x4 a = *(const f32x4*)sr;
    f32x4 b = *(const f32x4*)(sr + 4);
    float m = fmaxf(fmaxf(fmaxf(a[0], a[1]), fmaxf(a[2], a[3])),
                    fmaxf(fmaxf(b[0], b[1]), fmaxf(b[2], b[3])));
#pragma unroll
    for (int off = 32; off; off >>= 1) m = fmaxf(m, __shfl_xor(m, off));
    __shared__ float redm[4], reds[4];
    if ((t & 63) == 0) redm[t >> 6] = m;
    __syncthreads();
    m = fmaxf(fmaxf(redm[0], redm[1]), fmaxf(redm[2], redm[3]));

    float e[8];
    e[0] = __expf(a[0] - m); e[1] = __expf(a[1] - m);
    e[2] = __expf(a[2] - m); e[3] = __expf(a[3] - m);
    e[4] = __expf(b[0] - m); e[5] = __expf(b[1] - m);
    e[6] = __expf(b[2] - m); e[7] = __expf(b[3] - m);
    float s = ((e[0] + e[1]) + (e[2] + e[3])) + ((e[4] + e[5]) + (e[6] + e[7]));
#pragma unroll
    for (int off = 32; off; off >>= 1) s += __shfl_xor(s, off);
    if ((t & 63) == 0) reds[t >> 6] = s;
    __syncthreads();
    s = (reds[0] + reds[1]) + (reds[2] + reds[3]);
    float inv = 1.0f / s;
    f16x8 o;
#pragma unroll
    for (int i = 0; i < 8; ++i) o[i] = (h16)(e[i] * inv);
    *(f16x8*)(P + (size_t)row * 2048 + t * 8) = o;
}

extern "C" void kernel_launch(void* const* d_in, const int* in_sizes, int n_in,
                              void* d_out, int out_size, void* d_ws, size_t ws_size,
                              hipStream_t stream) {
    (void)in_sizes; (void)n_in; (void)out_size; (void)ws_size;
    const float* X  = (const float*)d_in[0];
    const float* Wq = (const float*)d_in[1];
    const float* Wk = (const float*)d_in[2];
    const float* Wv = (const float*)d_in[3];

    char* ws = (char*)d_ws;
    h16*   Xh = (h16*)ws;
    h16*   Wt = (h16*)(ws + 33554432);
    h16*   Vt = (h16*)(ws + 39845888);
    float* S  = (float*)(ws + 73400320);
    h16*   P  = (h16*)(ws + 90177536);
    h16*   QK = (h16*)d_out;     // per-batch [Q_b | K_b] fp16 chunks
    float* O  = (float*)d_out;

    k_convX<<<8192, 256, 0, stream>>>(X, Xh);
    k_convW<<<768, 256, 0, stream>>>(Wq, Wk, Wv, Wt);
    k_gemm_qkv<<<3072, 256, 0, stream>>>(Xh, Wt, QK, Vt);

    for (int b = 0; b < 8; ++b) {
        const h16* Qb  = QK + (size_t)b * 4194304;
        const h16* Kb  = Qb + 2097152;
        const h16* Vtb = Vt + (size_t)b * 2097152;
        float*     Ob  = O  + (size_t)b * 2097152;
        // S = Q_b @ K_b^T   [2048 x 2048], K=1024
        k_gemm_f32<<<256, 256, 0, stream>>>(Qb, Kb, S, 1024, 1024, 2048, 1024, 16);
        // P = softmax(S)
        k_softmax<<<2048, 256, 0, stream>>>(S, P);
        // O_b = P @ V_b = P @ Vt_b^T   [2048 x 1024], K=2048  (overwrites Q_b|K_b region)
        k_gemm_f32<<<128, 256, 0, stream>>>(P, Vtb, Ob, 2048, 2048, 1024, 2048, 8);
    }
}

// Round 4
// 518.121 us; speedup vs baseline: 1.5403x; 1.5403x over previous
//
#include <hip/hip_runtime.h>
#include <stdint.h>

typedef _Float16 h16;
typedef __attribute__((ext_vector_type(8))) _Float16 f16x8;
typedef __attribute__((ext_vector_type(4))) float f32x4;

// Problem: B=8, T=2048, D=1024, NODES=1024  (fp32 in/out)
// ws layout (bytes):
//   Xh  @ 0         : 33554432   (X fp16)          -- dead after qkv GEMM
//   Wt  @ 33554432  : 6291456    (W^T fp16 [n][d]) -- dead after qkv GEMM
//   Vt  @ 39845888  : 33554432   (V^T fp16 [b][n][t]) -- live to end
//   S   @ 0         : 33554432   (group of 2 batches, fp32 scores; reuses Xh)
//   P   @ 73400320  : 16777216   (group of 2 batches, fp16 probs)
// peak = 90177536 (~86 MiB)
// Q,K fp16 live in d_out: per-batch 8 MiB chunk [Q_b | K_b]; batch b's fp32
// output exactly overwrites [Q_b|K_b] after they are consumed by its S GEMM.

#define GLD16(gsrc, ldst)                                                     \
    __builtin_amdgcn_global_load_lds(                                         \
        (const __attribute__((address_space(1))) uint32_t*)(gsrc),            \
        (__attribute__((address_space(3))) uint32_t*)(ldst), 16, 0, 0)

// ---------------- convert X fp32 -> fp16 ----------------
__global__ __launch_bounds__(256) void k_convX(const float* __restrict__ X,
                                               h16* __restrict__ Xh) {
    size_t i = ((size_t)blockIdx.x * 256 + threadIdx.x) * 8;
    f32x4 a = *(const f32x4*)(X + i);
    f32x4 b = *(const f32x4*)(X + i + 4);
    f16x8 o;
    o[0] = (h16)a[0]; o[1] = (h16)a[1]; o[2] = (h16)a[2]; o[3] = (h16)a[3];
    o[4] = (h16)b[0]; o[5] = (h16)b[1]; o[6] = (h16)b[2]; o[7] = (h16)b[3];
    *(f16x8*)(Xh + i) = o;
}

// ---------------- transpose+convert W [d][n] fp32 -> Wt [n][d] fp16 ----------------
__global__ __launch_bounds__(256) void k_convW(const float* __restrict__ W0,
                                               const float* __restrict__ W1,
                                               const float* __restrict__ W2,
                                               h16* __restrict__ Wt) {
    __shared__ h16 LT[64 * 72];
    int which = blockIdx.x >> 8;
    int tile  = blockIdx.x & 255;
    int d0 = (tile >> 4) * 64, n0 = (tile & 15) * 64;
    const float* W = (which == 0) ? W0 : ((which == 1) ? W1 : W2);
    h16* dst = Wt + (size_t)which * (1024 * 1024);
    int t = threadIdx.x;
#pragma unroll
    for (int p = 0; p < 4; ++p) {
        int c = t + p * 256;
        int r = c >> 4;
        int cf = (c & 15) * 4;
        f32x4 v = *(const f32x4*)&W[(size_t)(d0 + r) * 1024 + n0 + cf];
#pragma unroll
        for (int e = 0; e < 4; ++e) LT[(cf + e) * 72 + r] = (h16)v[e];
    }
    __syncthreads();
#pragma unroll
    for (int p = 0; p < 2; ++p) {
        int q = t + p * 256;
        int nl = q >> 3;
        int dc = (q & 7) * 8;
        f16x8 v = *(f16x8*)&LT[nl * 72 + dc];
        *(f16x8*)&dst[(size_t)(n0 + nl) * 1024 + d0 + dc] = v;
    }
}

// ---------------- shared 128x128 GEMM core (A row-major, B^T row-major) ----------------
// 256 threads = 4 waves (2x2 of 64x64); BK=32; mfma_f32_16x16x32_f16
// Staging via global_load_lds width-16: LDS dest linear in lane order.
__device__ __forceinline__ void gemm_tile(const h16* __restrict__ A,
                                          const h16* __restrict__ Bt,
                                          int K, int lda, int ldb,
                                          int rowBase, int colBase,
                                          h16* lA, h16* lB, f32x4 acc[4][4]) {
    const int t = threadIdx.x;
    const int lane = t & 63, wave = t >> 6;
    const int wr = wave >> 1, wc = wave & 1;
    const int fr = lane & 15, fk = (lane >> 4) * 8;

    const int c0 = t, c1 = t + 256;
    const int r0 = c0 >> 2, k00 = (c0 & 3) * 8;
    const int r1 = c1 >> 2, k01 = (c1 & 3) * 8;
    const h16* Ap0 = A + (size_t)(rowBase + r0) * lda + k00;
    const h16* Ap1 = A + (size_t)(rowBase + r1) * lda + k01;
    const h16* Bp0 = Bt + (size_t)(colBase + r0) * ldb + k00;
    const h16* Bp1 = Bt + (size_t)(colBase + r1) * ldb + k01;
    h16* sA0 = lA + c0 * 8; h16* sA1 = lA + c1 * 8;
    h16* sB0 = lB + c0 * 8; h16* sB1 = lB + c1 * 8;

    for (int kt = 0; kt < K; kt += 32) {
        GLD16(Ap0 + kt, sA0);
        GLD16(Ap1 + kt, sA1);
        GLD16(Bp0 + kt, sB0);
        GLD16(Bp1 + kt, sB1);
        __syncthreads();  // drains vmcnt before any wave reads LDS
        f16x8 af[4], bf[4];
#pragma unroll
        for (int m = 0; m < 4; ++m)
            af[m] = *(const f16x8*)&lA[(wr * 64 + m * 16 + fr) * 32 + fk];
#pragma unroll
        for (int n = 0; n < 4; ++n)
            bf[n] = *(const f16x8*)&lB[(wc * 64 + n * 16 + fr) * 32 + fk];
#pragma unroll
        for (int m = 0; m < 4; ++m)
#pragma unroll
            for (int n = 0; n < 4; ++n)
                acc[m][n] = __builtin_amdgcn_mfma_f32_16x16x32_f16(af[m], bf[n], acc[m][n], 0, 0, 0);
        __syncthreads();  // all waves done reading before next tile overwrites
    }
}

// ---------------- fused QKV projection GEMM ----------------
__global__ __launch_bounds__(256) void k_gemm_qkv(const h16* __restrict__ Xh,
                                                  const h16* __restrict__ Wt,
                                                  h16* __restrict__ qk,
                                                  h16* __restrict__ vt) {
    __shared__ char smem[34816];  // max(16 KiB staging, 128*136*2 transpose)
    h16* lA = (h16*)smem;
    h16* lB = (h16*)(smem + 8192);

    int bid = blockIdx.x;
    int nt = bid % 24, mt = bid / 24;
    int rowBase = mt * 128, colBaseF = nt * 128;
    int which = colBaseF >> 10;     // 0=Q 1=K 2=V
    int nc0 = colBaseF & 1023;
    const h16* Bt = Wt + (size_t)which * (1024 * 1024);

    f32x4 acc[4][4];
#pragma unroll
    for (int m = 0; m < 4; ++m)
#pragma unroll
        for (int n = 0; n < 4; ++n) acc[m][n] = (f32x4){0.f, 0.f, 0.f, 0.f};

    gemm_tile(Xh, Bt, 1024, 1024, 1024, rowBase, nc0, lA, lB, acc);

    const int t = threadIdx.x;
    const int lane = t & 63, wave = t >> 6;
    const int wr = wave >> 1, wc = wave & 1;
    const int fr = lane & 15, fj = (lane >> 4) * 4;
    const int b = rowBase >> 11;
    const int tloc = rowBase & 2047;

    if (which < 2) {
        h16* dst = qk + (size_t)b * 4194304 + (which == 1 ? 2097152u : 0u);
#pragma unroll
        for (int m = 0; m < 4; ++m)
#pragma unroll
            for (int n = 0; n < 4; ++n) {
                int cc = nc0 + wc * 64 + n * 16 + fr;
#pragma unroll
                for (int j = 0; j < 4; ++j) {
                    int rr = tloc + wr * 64 + m * 16 + fj + j;
                    dst[(size_t)rr * 1024 + cc] = (h16)acc[m][n][j];
                }
            }
    } else {
        // transpose epilogue through LDS: write Vt[b][n][t]
        h16* LTm = (h16*)smem;  // [128 n][136]
        __syncthreads();        // staging LDS reuse
#pragma unroll
        for (int m = 0; m < 4; ++m)
#pragma unroll
            for (int n = 0; n < 4; ++n) {
                int cloc = wc * 64 + n * 16 + fr;
#pragma unroll
                for (int j = 0; j < 4; ++j) {
                    int rloc = wr * 64 + m * 16 + fj + j;
                    LTm[cloc * 136 + rloc] = (h16)acc[m][n][j];
                }
            }
        __syncthreads();
#pragma unroll
        for (int p = 0; p < 8; ++p) {
            int q = t + p * 256;
            int nl = q >> 4;
            int tc = (q & 15) * 8;
            f16x8 v = *(f16x8*)&LTm[nl * 136 + tc];
            *(f16x8*)&vt[(size_t)b * 2097152 + (size_t)(nc0 + nl) * 2048 + tloc + tc] = v;
        }
    }
}

// ---------------- batched fp32-output GEMM (scores and out), blockIdx.y = sub-batch ----
__global__ __launch_bounds__(256) void k_gemm_f32b(const h16* __restrict__ A,
                                                   const h16* __restrict__ Bt,
                                                   float* __restrict__ C,
                                                   int lda, int ldb, int ldc,
                                                   int K, int ntiles,
                                                   size_t sA, size_t sB, size_t sC) {
    __shared__ char smem[16384];
    h16* lA = (h16*)smem;
    h16* lB = (h16*)(smem + 8192);

    const h16* Ab = A + (size_t)blockIdx.y * sA;
    const h16* Bb = Bt + (size_t)blockIdx.y * sB;
    float*     Cb = C + (size_t)blockIdx.y * sC;

    int nt = blockIdx.x % ntiles, mt = blockIdx.x / ntiles;
    int rowBase = mt * 128, colBase = nt * 128;

    f32x4 acc[4][4];
#pragma unroll
    for (int m = 0; m < 4; ++m)
#pragma unroll
        for (int n = 0; n < 4; ++n) acc[m][n] = (f32x4){0.f, 0.f, 0.f, 0.f};

    gemm_tile(Ab, Bb, K, lda, ldb, rowBase, colBase, lA, lB, acc);

    const int t = threadIdx.x;
    const int lane = t & 63, wave = t >> 6;
    const int wr = wave >> 1, wc = wave & 1;
    const int fr = lane & 15, fj = (lane >> 4) * 4;
#pragma unroll
    for (int m = 0; m < 4; ++m)
#pragma unroll
        for (int n = 0; n < 4; ++n) {
            int cc = colBase + wc * 64 + n * 16 + fr;
#pragma unroll
            for (int j = 0; j < 4; ++j) {
                int rr = rowBase + wr * 64 + m * 16 + fj + j;
                Cb[(size_t)rr * ldc + cc] = acc[m][n][j];
            }
        }
}

// ---------------- row softmax over group: S fp32 [rows][2048] -> P fp16 ----------------
__global__ __launch_bounds__(256) void k_softmax(const float* __restrict__ S,
                                                 h16* __restrict__ P) {
    int row = blockIdx.x, t = threadIdx.x;
    const float* sr = S + (size_t)row * 2048 + t * 8;
    f32x4 a = *(const f32x4*)sr;
    f32x4 b = *(const f32x4*)(sr + 4);
    float m = fmaxf(fmaxf(fmaxf(a[0], a[1]), fmaxf(a[2], a[3])),
                    fmaxf(fmaxf(b[0], b[1]), fmaxf(b[2], b[3])));
#pragma unroll
    for (int off = 32; off; off >>= 1) m = fmaxf(m, __shfl_xor(m, off));
    __shared__ float redm[4], reds[4];
    if ((t & 63) == 0) redm[t >> 6] = m;
    __syncthreads();
    m = fmaxf(fmaxf(redm[0], redm[1]), fmaxf(redm[2], redm[3]));

    float e[8];
    e[0] = __expf(a[0] - m); e[1] = __expf(a[1] - m);
    e[2] = __expf(a[2] - m); e[3] = __expf(a[3] - m);
    e[4] = __expf(b[0] - m); e[5] = __expf(b[1] - m);
    e[6] = __expf(b[2] - m); e[7] = __expf(b[3] - m);
    float s = ((e[0] + e[1]) + (e[2] + e[3])) + ((e[4] + e[5]) + (e[6] + e[7]));
#pragma unroll
    for (int off = 32; off; off >>= 1) s += __shfl_xor(s, off);
    if ((t & 63) == 0) reds[t >> 6] = s;
    __syncthreads();
    s = (reds[0] + reds[1]) + (reds[2] + reds[3]);
    float inv = 1.0f / s;
    f16x8 o;
#pragma unroll
    for (int i = 0; i < 8; ++i) o[i] = (h16)(e[i] * inv);
    *(f16x8*)(P + (size_t)row * 2048 + t * 8) = o;
}

extern "C" void kernel_launch(void* const* d_in, const int* in_sizes, int n_in,
                              void* d_out, int out_size, void* d_ws, size_t ws_size,
                              hipStream_t stream) {
    (void)in_sizes; (void)n_in; (void)out_size; (void)ws_size;
    const float* X  = (const float*)d_in[0];
    const float* Wq = (const float*)d_in[1];
    const float* Wk = (const float*)d_in[2];
    const float* Wv = (const float*)d_in[3];

    char* ws = (char*)d_ws;
    h16*   Xh = (h16*)ws;
    h16*   Wt = (h16*)(ws + 33554432);
    h16*   Vt = (h16*)(ws + 39845888);
    float* S  = (float*)ws;               // reuses dead Xh region (group of 2)
    h16*   P  = (h16*)(ws + 73400320);    // group of 2
    h16*   QK = (h16*)d_out;
    float* O  = (float*)d_out;

    k_convX<<<8192, 256, 0, stream>>>(X, Xh);
    k_convW<<<768, 256, 0, stream>>>(Wq, Wk, Wv, Wt);
    k_gemm_qkv<<<3072, 256, 0, stream>>>(Xh, Wt, QK, Vt);

    for (int g = 0; g < 4; ++g) {
        const h16* Qg  = QK + (size_t)g * 2 * 4194304;           // [Q|K] chunks, stride 4Mi halves
        const h16* Vtg = Vt + (size_t)g * 2 * 2097152;
        float*     Og  = O  + (size_t)g * 2 * 2097152;
        // S[i] = Q_i @ K_i^T   [2048 x 2048], K=1024   (2 sub-batches)
        k_gemm_f32b<<<dim3(256, 2), 256, 0, stream>>>(
            Qg, Qg + 2097152, S, 1024, 1024, 2048, 1024, 16,
            (size_t)4194304, (size_t)4194304, (size_t)4194304);
        // P = softmax(S)  (2 batches = 4096 rows)
        k_softmax<<<4096, 256, 0, stream>>>(S, P);
        // O_i = P_i @ Vt_i^T   [2048 x 1024], K=2048  (overwrites spent Q_i|K_i)
        k_gemm_f32b<<<dim3(128, 2), 256, 0, stream>>>(
            P, Vtg, Og, 2048, 2048, 1024, 2048, 8,
            (size_t)4194304, (size_t)2097152, (size_t)2097152);
    }
}

// Round 5
// 504.297 us; speedup vs baseline: 1.5826x; 1.0274x over previous
//
#include <hip/hip_runtime.h>
#include <stdint.h>

typedef _Float16 h16;
typedef __attribute__((ext_vector_type(8))) _Float16 f16x8;
typedef __attribute__((ext_vector_type(4))) float f32x4;

// Problem: B=8, T=2048, D=1024, NODES=1024  (fp32 in/out)
// ws layout (bytes):
//   Xh  @ 0         : 33554432   (X fp16)          -- dead after qkv GEMM
//   Wt  @ 33554432  : 6291456    (W^T fp16 [n][d]) -- dead after qkv GEMM
//   Vt  @ 39845888  : 33554432   (V^T fp16 [b][n][t]) -- live to end
//   S   @ 0         : 33554432   (group of 2 batches, fp32 scores; reuses Xh)
//   P   @ 73400320  : 16777216   (group of 2 batches, fp16 probs)
// Q,K fp16 live in d_out: per-batch 8 MiB chunk [Q_b | K_b]; batch b's fp32
// output exactly overwrites [Q_b|K_b] after they are consumed by its S GEMM.

#define GLD16(gsrc, ldst)                                                     \
    __builtin_amdgcn_global_load_lds(                                         \
        (const __attribute__((address_space(1))) uint32_t*)(gsrc),            \
        (__attribute__((address_space(3))) uint32_t*)(ldst), 16, 0, 0)

#define FENCE asm volatile("" ::: "memory")
#define BARRIER do { FENCE; __builtin_amdgcn_s_barrier(); FENCE; } while (0)
#define LGKM0  asm volatile("s_waitcnt lgkmcnt(0)" ::: "memory")
#define VMCNT4 asm volatile("s_waitcnt vmcnt(4)" ::: "memory")
#define VMCNT0 asm volatile("s_waitcnt vmcnt(0)" ::: "memory")

// ---------------- convert X fp32 -> fp16 ----------------
__global__ __launch_bounds__(256) void k_convX(const float* __restrict__ X,
                                               h16* __restrict__ Xh) {
    size_t i = ((size_t)blockIdx.x * 256 + threadIdx.x) * 8;
    f32x4 a = *(const f32x4*)(X + i);
    f32x4 b = *(const f32x4*)(X + i + 4);
    f16x8 o;
    o[0] = (h16)a[0]; o[1] = (h16)a[1]; o[2] = (h16)a[2]; o[3] = (h16)a[3];
    o[4] = (h16)b[0]; o[5] = (h16)b[1]; o[6] = (h16)b[2]; o[7] = (h16)b[3];
    *(f16x8*)(Xh + i) = o;
}

// ---------------- transpose+convert W [d][n] fp32 -> Wt [n][d] fp16 ----------------
__global__ __launch_bounds__(256) void k_convW(const float* __restrict__ W0,
                                               const float* __restrict__ W1,
                                               const float* __restrict__ W2,
                                               h16* __restrict__ Wt) {
    __shared__ h16 LT[64 * 72];
    int which = blockIdx.x >> 8;
    int tile  = blockIdx.x & 255;
    int d0 = (tile >> 4) * 64, n0 = (tile & 15) * 64;
    const float* W = (which == 0) ? W0 : ((which == 1) ? W1 : W2);
    h16* dst = Wt + (size_t)which * (1024 * 1024);
    int t = threadIdx.x;
#pragma unroll
    for (int p = 0; p < 4; ++p) {
        int c = t + p * 256;
        int r = c >> 4;
        int cf = (c & 15) * 4;
        f32x4 v = *(const f32x4*)&W[(size_t)(d0 + r) * 1024 + n0 + cf];
#pragma unroll
        for (int e = 0; e < 4; ++e) LT[(cf + e) * 72 + r] = (h16)v[e];
    }
    __syncthreads();
#pragma unroll
    for (int p = 0; p < 2; ++p) {
        int q = t + p * 256;
        int nl = q >> 3;
        int dc = (q & 7) * 8;
        f16x8 v = *(f16x8*)&LT[nl * 72 + dc];
        *(f16x8*)&dst[(size_t)(n0 + nl) * 1024 + d0 + dc] = v;
    }
}

// ============ 256x256 8-phase QKV GEMM (T2+T3+T4+T5) ============
// 512 threads = 8 waves (wr 0..1, wc 0..3). Wave output: rows {mh*128+wr*64+..}
// cols {nh*128+wc*32+..}. BK=64, double-buffered 128 KiB LDS.
// LDS: A @ buf*32768, B @ 65536 + buf*32768; tile[256 rows][8 slots of 16B],
// physical slot = logical slot ^ (row&7) (bank swizzle; staged via
// inverse-swizzled GLOBAL source + linear global_load_lds dest).
__global__ __launch_bounds__(512, 2) void k_gemm_qkv256(const h16* __restrict__ Xh,
                                                        const h16* __restrict__ Wt,
                                                        h16* __restrict__ qk,
                                                        h16* __restrict__ vt) {
    extern __shared__ char smem[];
    const int t = threadIdx.x;
    const int lane = t & 63, wave = t >> 6;
    const int wr = wave >> 2, wc = wave & 3;
    const int fr = lane & 15, kq = lane >> 4;
    const int sw = fr & 7;
    const int loff = (((t & 7) ^ ((t >> 3) & 7)) * 8);  // inverse-swizzle k-offset (halves)

    int bid = blockIdx.x;
    bid = (bid & 7) * 96 + (bid >> 3);        // XCD swizzle (768 % 8 == 0)
    const int nt = bid % 12, mt = bid / 12;
    const int rowBase = mt * 256;
    const int colBaseF = nt * 256;
    const int which = nt >> 2;                // 0=Q 1=K 2=V
    const int nc0 = colBaseF & 1023;
    const h16* A  = Xh;
    const h16* Bt = Wt + (size_t)which * (1024 * 1024);

#define STAGE_OP(OPREG, OPPTR, OPROW, BUF, H, KT) do {                          \
        const h16* _src = (OPPTR) + (size_t)((OPROW) + (H) * 128 + (t >> 3)) * 1024 \
                          + (KT) * 64 + loff;                                   \
        char* _dst = smem + (OPREG) + (BUF) * 32768 + (H) * 16384 + t * 16;     \
        GLD16(_src, _dst);                                                      \
        GLD16(_src + 64 * 1024, _dst + 8192);                                   \
    } while (0)
#define STAGE_A(BUF, H, KT) STAGE_OP(0, A, rowBase, BUF, H, KT)
#define STAGE_B(BUF, H, KT) STAGE_OP(65536, Bt, nc0, BUF, H, KT)

#define RD(REG, ROW, SLOT) \
    (*(const f16x8*)(smem + (REG) + (ROW) * 128 + ((((SLOT)) ^ sw) << 4)))

    f32x4 acc[2][2][4][2];
#pragma unroll
    for (int mh = 0; mh < 2; ++mh)
#pragma unroll
        for (int nh = 0; nh < 2; ++nh)
#pragma unroll
            for (int q = 0; q < 4; ++q)
#pragma unroll
                for (int nf = 0; nf < 2; ++nf)
                    acc[mh][nh][q][nf] = (f32x4){0.f, 0.f, 0.f, 0.f};

    f16x8 a[4][2], b[2][2];

#define PH(BUF, MH, NH, DOA, STG, VM) do {                                      \
        if (DOA) {                                                              \
            _Pragma("unroll") for (int q = 0; q < 4; ++q)                       \
            _Pragma("unroll") for (int ks = 0; ks < 2; ++ks)                    \
                a[q][ks] = RD((BUF) * 32768,                                    \
                              (MH) * 128 + wr * 64 + q * 16 + fr, kq + ks * 4); \
        }                                                                       \
        _Pragma("unroll") for (int nf = 0; nf < 2; ++nf)                        \
        _Pragma("unroll") for (int ks = 0; ks < 2; ++ks)                        \
            b[nf][ks] = RD(65536 + (BUF) * 32768,                               \
                           (NH) * 128 + wc * 32 + nf * 16 + fr, kq + ks * 4);   \
        STG;                                                                    \
        VM;                                                                     \
        BARRIER; LGKM0;                                                         \
        __builtin_amdgcn_s_setprio(1);                                          \
        _Pragma("unroll") for (int q = 0; q < 4; ++q)                           \
        _Pragma("unroll") for (int nf = 0; nf < 2; ++nf)                        \
        _Pragma("unroll") for (int ks = 0; ks < 2; ++ks)                        \
            acc[MH][NH][q][nf] = __builtin_amdgcn_mfma_f32_16x16x32_f16(        \
                a[q][ks], b[nf][ks], acc[MH][NH][q][nf], 0, 0, 0);              \
        __builtin_amdgcn_s_setprio(0);                                          \
        BARRIER;                                                                \
    } while (0)

    // Prologue: tile0 full -> buf0; tile1 A-h0,B-h0 -> buf1.
    STAGE_A(0, 0, 0); STAGE_A(0, 1, 0);
    STAGE_B(0, 0, 0); STAGE_B(0, 1, 0);
    STAGE_A(1, 0, 1); STAGE_B(1, 0, 1);
    VMCNT4;           // tile0's 8 loads landed (keep tile1's 4 in flight)
    BARRIER;

    // K = 1024 -> 16 K-tiles of 64, 2 per iteration.
    for (int i = 0; i < 8; ++i) {
        const int tb  = 2 * i + 1;
        const int tc2 = (2 * i + 2) & 15;
        const int td  = (2 * i + 3) & 15;
        PH(0, 0, 0, 1, STAGE_A(1, 1, tb),  (void)0);
        PH(0, 0, 1, 0, STAGE_B(1, 1, tb),  (void)0);
        PH(0, 1, 0, 1, STAGE_A(0, 0, tc2), (void)0);
        PH(0, 1, 1, 0, STAGE_B(0, 0, tc2), VMCNT4);
        PH(1, 0, 0, 1, STAGE_A(0, 1, tc2), (void)0);
        PH(1, 0, 1, 0, STAGE_B(0, 1, tc2), (void)0);
        PH(1, 1, 0, 1, STAGE_A(1, 0, td),  (void)0);
        PH(1, 1, 1, 0, STAGE_B(1, 0, td),  VMCNT4);
    }

    VMCNT0;   // drain stray prefetches before LDS reuse / exit
    BARRIER;

    const int bat  = rowBase >> 11;
    const int tloc = rowBase & 2047;

    if (which < 2) {
        h16* dst = qk + (size_t)bat * 4194304 + (which == 1 ? 2097152u : 0u);
#pragma unroll
        for (int mh = 0; mh < 2; ++mh)
#pragma unroll
            for (int nh = 0; nh < 2; ++nh)
#pragma unroll
                for (int q = 0; q < 4; ++q)
#pragma unroll
                    for (int nf = 0; nf < 2; ++nf) {
                        int cc = nc0 + nh * 128 + wc * 32 + nf * 16 + fr;
#pragma unroll
                        for (int j = 0; j < 4; ++j) {
                            int rr = tloc + mh * 128 + wr * 64 + q * 16 + kq * 4 + j;
                            dst[(size_t)rr * 1024 + cc] = (h16)acc[mh][nh][q][nf][j];
                        }
                    }
    } else {
        // V: transpose through (reused) staging LDS -> Vt[b][n][t]
        h16* LT = (h16*)smem;  // [256 n][136 t-pad]
        const size_t bvt = (size_t)bat * 2097152;
#pragma unroll
        for (int mh = 0; mh < 2; ++mh) {
            __syncthreads();
#pragma unroll
            for (int nh = 0; nh < 2; ++nh)
#pragma unroll
                for (int q = 0; q < 4; ++q)
#pragma unroll
                    for (int nf = 0; nf < 2; ++nf) {
                        int cl = nh * 128 + wc * 32 + nf * 16 + fr;
#pragma unroll
                        for (int j = 0; j < 4; ++j) {
                            int rl = wr * 64 + q * 16 + kq * 4 + j;
                            LT[cl * 136 + rl] = (h16)acc[mh][nh][q][nf][j];
                        }
                    }
            __syncthreads();
#pragma unroll
            for (int p = 0; p < 8; ++p) {
                int idx = t + p * 512;
                int nl = idx >> 4;
                int tc = (idx & 15) * 8;
                *(f16x8*)&vt[bvt + (size_t)(nc0 + nl) * 2048 + tloc + mh * 128 + tc] =
                    *(f16x8*)&LT[nl * 136 + tc];
            }
        }
    }
#undef PH
#undef RD
#undef STAGE_A
#undef STAGE_B
#undef STAGE_OP
}

// ---------------- shared 128x128 GEMM core (A row-major, B^T row-major) ----------------
__device__ __forceinline__ void gemm_tile(const h16* __restrict__ A,
                                          const h16* __restrict__ Bt,
                                          int K, int lda, int ldb,
                                          int rowBase, int colBase,
                                          h16* lA, h16* lB, f32x4 acc[4][4]) {
    const int t = threadIdx.x;
    const int lane = t & 63, wave = t >> 6;
    const int wr = wave >> 1, wc = wave & 1;
    const int fr = lane & 15, fk = (lane >> 4) * 8;

    const int c0 = t, c1 = t + 256;
    const int r0 = c0 >> 2, k00 = (c0 & 3) * 8;
    const int r1 = c1 >> 2, k01 = (c1 & 3) * 8;
    const h16* Ap0 = A + (size_t)(rowBase + r0) * lda + k00;
    const h16* Ap1 = A + (size_t)(rowBase + r1) * lda + k01;
    const h16* Bp0 = Bt + (size_t)(colBase + r0) * ldb + k00;
    const h16* Bp1 = Bt + (size_t)(colBase + r1) * ldb + k01;
    h16* sA0 = lA + c0 * 8; h16* sA1 = lA + c1 * 8;
    h16* sB0 = lB + c0 * 8; h16* sB1 = lB + c1 * 8;

    for (int kt = 0; kt < K; kt += 32) {
        GLD16(Ap0 + kt, sA0);
        GLD16(Ap1 + kt, sA1);
        GLD16(Bp0 + kt, sB0);
        GLD16(Bp1 + kt, sB1);
        __syncthreads();
        f16x8 af[4], bf[4];
#pragma unroll
        for (int m = 0; m < 4; ++m)
            af[m] = *(const f16x8*)&lA[(wr * 64 + m * 16 + fr) * 32 + fk];
#pragma unroll
        for (int n = 0; n < 4; ++n)
            bf[n] = *(const f16x8*)&lB[(wc * 64 + n * 16 + fr) * 32 + fk];
#pragma unroll
        for (int m = 0; m < 4; ++m)
#pragma unroll
            for (int n = 0; n < 4; ++n)
                acc[m][n] = __builtin_amdgcn_mfma_f32_16x16x32_f16(af[m], bf[n], acc[m][n], 0, 0, 0);
        __syncthreads();
    }
}

// ---------------- batched fp32-output GEMM (scores and out), blockIdx.y = sub-batch ----
__global__ __launch_bounds__(256) void k_gemm_f32b(const h16* __restrict__ A,
                                                   const h16* __restrict__ Bt,
                                                   float* __restrict__ C,
                                                   int lda, int ldb, int ldc,
                                                   int K, int ntiles,
                                                   size_t sA, size_t sB, size_t sC) {
    __shared__ char smem2[16384];
    h16* lA = (h16*)smem2;
    h16* lB = (h16*)(smem2 + 8192);

    const h16* Ab = A + (size_t)blockIdx.y * sA;
    const h16* Bb = Bt + (size_t)blockIdx.y * sB;
    float*     Cb = C + (size_t)blockIdx.y * sC;

    int nt = blockIdx.x % ntiles, mt = blockIdx.x / ntiles;
    int rowBase = mt * 128, colBase = nt * 128;

    f32x4 acc[4][4];
#pragma unroll
    for (int m = 0; m < 4; ++m)
#pragma unroll
        for (int n = 0; n < 4; ++n) acc[m][n] = (f32x4){0.f, 0.f, 0.f, 0.f};

    gemm_tile(Ab, Bb, K, lda, ldb, rowBase, colBase, lA, lB, acc);

    const int t = threadIdx.x;
    const int lane = t & 63, wave = t >> 6;
    const int wr = wave >> 1, wc = wave & 1;
    const int fr = lane & 15, fj = (lane >> 4) * 4;
#pragma unroll
    for (int m = 0; m < 4; ++m)
#pragma unroll
        for (int n = 0; n < 4; ++n) {
            int cc = colBase + wc * 64 + n * 16 + fr;
#pragma unroll
            for (int j = 0; j < 4; ++j) {
                int rr = rowBase + wr * 64 + m * 16 + fj + j;
                Cb[(size_t)rr * ldc + cc] = acc[m][n][j];
            }
        }
}

// ---------------- row softmax over group: S fp32 [rows][2048] -> P fp16 ----------------
__global__ __launch_bounds__(256) void k_softmax(const float* __restrict__ S,
                                                 h16* __restrict__ P) {
    int row = blockIdx.x, t = threadIdx.x;
    const float* sr = S + (size_t)row * 2048 + t * 8;
    f32x4 a = *(const f32x4*)sr;
    f32x4 b = *(const f32x4*)(sr + 4);
    float m = fmaxf(fmaxf(fmaxf(a[0], a[1]), fmaxf(a[2], a[3])),
                    fmaxf(fmaxf(b[0], b[1]), fmaxf(b[2], b[3])));
#pragma unroll
    for (int off = 32; off; off >>= 1) m = fmaxf(m, __shfl_xor(m, off));
    __shared__ float redm[4], reds[4];
    if ((t & 63) == 0) redm[t >> 6] = m;
    __syncthreads();
    m = fmaxf(fmaxf(redm[0], redm[1]), fmaxf(redm[2], redm[3]));

    float e[8];
    e[0] = __expf(a[0] - m); e[1] = __expf(a[1] - m);
    e[2] = __expf(a[2] - m); e[3] = __expf(a[3] - m);
    e[4] = __expf(b[0] - m); e[5] = __expf(b[1] - m);
    e[6] = __expf(b[2] - m); e[7] = __expf(b[3] - m);
    float s = ((e[0] + e[1]) + (e[2] + e[3])) + ((e[4] + e[5]) + (e[6] + e[7]));
#pragma unroll
    for (int off = 32; off; off >>= 1) s += __shfl_xor(s, off);
    if ((t & 63) == 0) reds[t >> 6] = s;
    __syncthreads();
    s = (reds[0] + reds[1]) + (reds[2] + reds[3]);
    float inv = 1.0f / s;
    f16x8 o;
#pragma unroll
    for (int i = 0; i < 8; ++i) o[i] = (h16)(e[i] * inv);
    *(f16x8*)(P + (size_t)row * 2048 + t * 8) = o;
}

extern "C" void kernel_launch(void* const* d_in, const int* in_sizes, int n_in,
                              void* d_out, int out_size, void* d_ws, size_t ws_size,
                              hipStream_t stream) {
    (void)in_sizes; (void)n_in; (void)out_size; (void)ws_size;
    const float* X  = (const float*)d_in[0];
    const float* Wq = (const float*)d_in[1];
    const float* Wk = (const float*)d_in[2];
    const float* Wv = (const float*)d_in[3];

    char* ws = (char*)d_ws;
    h16*   Xh = (h16*)ws;
    h16*   Wt = (h16*)(ws + 33554432);
    h16*   Vt = (h16*)(ws + 39845888);
    float* S  = (float*)ws;               // reuses dead Xh region (group of 2)
    h16*   P  = (h16*)(ws + 73400320);    // group of 2
    h16*   QK = (h16*)d_out;
    float* O  = (float*)d_out;

    hipFuncSetAttribute((const void*)k_gemm_qkv256,
                        hipFuncAttributeMaxDynamicSharedMemorySize, 131072);

    k_convX<<<8192, 256, 0, stream>>>(X, Xh);
    k_convW<<<768, 256, 0, stream>>>(Wq, Wk, Wv, Wt);
    k_gemm_qkv256<<<768, 512, 131072, stream>>>(Xh, Wt, QK, Vt);

    for (int g = 0; g < 4; ++g) {
        const h16* Qg  = QK + (size_t)g * 2 * 4194304;
        const h16* Vtg = Vt + (size_t)g * 2 * 2097152;
        float*     Og  = O  + (size_t)g * 2 * 2097152;
        k_gemm_f32b<<<dim3(256, 2), 256, 0, stream>>>(
            Qg, Qg + 2097152, S, 1024, 1024, 2048, 1024, 16,
            (size_t)4194304, (size_t)4194304, (size_t)4194304);
        k_softmax<<<4096, 256, 0, stream>>>(S, P);
        k_gemm_f32b<<<dim3(128, 2), 256, 0, stream>>>(
            P, Vtg, Og, 2048, 2048, 1024, 2048, 8,
            (size_t)4194304, (size_t)2097152, (size_t)2097152);
    }
}

// Round 7
// 415.280 us; speedup vs baseline: 1.9218x; 1.2144x over previous
//
#include <hip/hip_runtime.h>
#include <stdint.h>

typedef _Float16 h16;
typedef __attribute__((ext_vector_type(8))) _Float16 f16x8;
typedef __attribute__((ext_vector_type(4))) float f32x4;

// Problem: B=8, T=2048, D=1024, NODES=1024  (fp32 in/out)
// ws layout (bytes):
//   Xh  @ 0         : 33554432   (X fp16)          -- dead after qkv GEMM
//   Wt  @ 33554432  : 6291456    (W^T fp16 [n][d]) -- dead after qkv GEMM
//   Vt  @ 39845888  : 33554432   (V^T fp16 [b][n][t]) -- live to end
//   S   @ 0         : 33554432   (group of 2 batches, fp32; reuses Xh)
//   P   @ 73400320  : 16777216   (group of 2 batches, fp16)
// Q,K fp16 live in d_out: per-batch 8 MiB chunk [Q_b | K_b]; batch b's fp32
// output exactly overwrites [Q_b|K_b] after its S GEMM consumed them.
// Launch chain: S0, SM0, [S1+O0], SM1, [S2+O1], SM2, [S3+O2], SM3, O3.

#define GLD16(gsrc, ldst)                                                     \
    __builtin_amdgcn_global_load_lds(                                         \
        (const __attribute__((address_space(1))) uint32_t*)(gsrc),            \
        (__attribute__((address_space(3))) uint32_t*)(ldst), 16, 0, 0)

#define FENCE asm volatile("" ::: "memory")
#define BARRIER do { FENCE; __builtin_amdgcn_s_barrier(); FENCE; } while (0)
#define LGKM0  asm volatile("s_waitcnt lgkmcnt(0)" ::: "memory")
#define VMCNT4 asm volatile("s_waitcnt vmcnt(4)" ::: "memory")
#define VMCNT0 asm volatile("s_waitcnt vmcnt(0)" ::: "memory")

// ---------------- convert X fp32 -> fp16 ----------------
__global__ __launch_bounds__(256) void k_convX(const float* __restrict__ X,
                                               h16* __restrict__ Xh) {
    size_t i = ((size_t)blockIdx.x * 256 + threadIdx.x) * 8;
    f32x4 a = *(const f32x4*)(X + i);
    f32x4 b = *(const f32x4*)(X + i + 4);
    f16x8 o;
    o[0] = (h16)a[0]; o[1] = (h16)a[1]; o[2] = (h16)a[2]; o[3] = (h16)a[3];
    o[4] = (h16)b[0]; o[5] = (h16)b[1]; o[6] = (h16)b[2]; o[7] = (h16)b[3];
    *(f16x8*)(Xh + i) = o;
}

// ---------------- transpose+convert W [d][n] fp32 -> Wt [n][d] fp16 ----------------
__global__ __launch_bounds__(256) void k_convW(const float* __restrict__ W0,
                                               const float* __restrict__ W1,
                                               const float* __restrict__ W2,
                                               h16* __restrict__ Wt) {
    __shared__ h16 LT[64 * 72];
    int which = blockIdx.x >> 8;
    int tile  = blockIdx.x & 255;
    int d0 = (tile >> 4) * 64, n0 = (tile & 15) * 64;
    const float* W = (which == 0) ? W0 : ((which == 1) ? W1 : W2);
    h16* dst = Wt + (size_t)which * (1024 * 1024);
    int t = threadIdx.x;
#pragma unroll
    for (int p = 0; p < 4; ++p) {
        int c = t + p * 256;
        int r = c >> 4;
        int cf = (c & 15) * 4;
        f32x4 v = *(const f32x4*)&W[(size_t)(d0 + r) * 1024 + n0 + cf];
#pragma unroll
        for (int e = 0; e < 4; ++e) LT[(cf + e) * 72 + r] = (h16)v[e];
    }
    __syncthreads();
#pragma unroll
    for (int p = 0; p < 2; ++p) {
        int q = t + p * 256;
        int nl = q >> 3;
        int dc = (q & 7) * 8;
        f16x8 v = *(f16x8*)&LT[nl * 72 + dc];
        *(f16x8*)&dst[(size_t)(n0 + nl) * 1024 + d0 + dc] = v;
    }
}

// ============ 256x256 8-phase QKV GEMM (T2+T3+T4+T5) — unchanged from r5 ============
__global__ __launch_bounds__(512, 2) void k_gemm_qkv256(const h16* __restrict__ Xh,
                                                        const h16* __restrict__ Wt,
                                                        h16* __restrict__ qk,
                                                        h16* __restrict__ vt) {
    extern __shared__ char smem[];
    const int t = threadIdx.x;
    const int lane = t & 63, wave = t >> 6;
    const int wr = wave >> 2, wc = wave & 3;
    const int fr = lane & 15, kq = lane >> 4;
    const int sw = fr & 7;
    const int loff = (((t & 7) ^ ((t >> 3) & 7)) * 8);

    int bid = blockIdx.x;
    bid = (bid & 7) * 96 + (bid >> 3);        // XCD swizzle (768 % 8 == 0)
    const int nt = bid % 12, mt = bid / 12;
    const int rowBase = mt * 256;
    const int colBaseF = nt * 256;
    const int which = nt >> 2;
    const int nc0 = colBaseF & 1023;
    const h16* A  = Xh;
    const h16* Bt = Wt + (size_t)which * (1024 * 1024);

#define STAGE_OP(OPREG, OPPTR, OPROW, BUF, H, KT) do {                          \
        const h16* _src = (OPPTR) + (size_t)((OPROW) + (H) * 128 + (t >> 3)) * 1024 \
                          + (KT) * 64 + loff;                                   \
        char* _dst = smem + (OPREG) + (BUF) * 32768 + (H) * 16384 + t * 16;     \
        GLD16(_src, _dst);                                                      \
        GLD16(_src + 64 * 1024, _dst + 8192);                                   \
    } while (0)
#define STAGE_A(BUF, H, KT) STAGE_OP(0, A, rowBase, BUF, H, KT)
#define STAGE_B(BUF, H, KT) STAGE_OP(65536, Bt, nc0, BUF, H, KT)

#define RD(REG, ROW, SLOT) \
    (*(const f16x8*)(smem + (REG) + (ROW) * 128 + ((((SLOT)) ^ sw) << 4)))

    f32x4 acc[2][2][4][2];
#pragma unroll
    for (int mh = 0; mh < 2; ++mh)
#pragma unroll
        for (int nh = 0; nh < 2; ++nh)
#pragma unroll
            for (int q = 0; q < 4; ++q)
#pragma unroll
                for (int nf = 0; nf < 2; ++nf)
                    acc[mh][nh][q][nf] = (f32x4){0.f, 0.f, 0.f, 0.f};

    f16x8 a[4][2], b[2][2];

#define PH(BUF, MH, NH, DOA, STG, VM) do {                                      \
        if (DOA) {                                                              \
            _Pragma("unroll") for (int q = 0; q < 4; ++q)                       \
            _Pragma("unroll") for (int ks = 0; ks < 2; ++ks)                    \
                a[q][ks] = RD((BUF) * 32768,                                    \
                              (MH) * 128 + wr * 64 + q * 16 + fr, kq + ks * 4); \
        }                                                                       \
        _Pragma("unroll") for (int nf = 0; nf < 2; ++nf)                        \
        _Pragma("unroll") for (int ks = 0; ks < 2; ++ks)                        \
            b[nf][ks] = RD(65536 + (BUF) * 32768,                               \
                           (NH) * 128 + wc * 32 + nf * 16 + fr, kq + ks * 4);   \
        STG;                                                                    \
        VM;                                                                     \
        BARRIER; LGKM0;                                                         \
        __builtin_amdgcn_s_setprio(1);                                          \
        _Pragma("unroll") for (int q = 0; q < 4; ++q)                           \
        _Pragma("unroll") for (int nf = 0; nf < 2; ++nf)                        \
        _Pragma("unroll") for (int ks = 0; ks < 2; ++ks)                        \
            acc[MH][NH][q][nf] = __builtin_amdgcn_mfma_f32_16x16x32_f16(        \
                a[q][ks], b[nf][ks], acc[MH][NH][q][nf], 0, 0, 0);              \
        __builtin_amdgcn_s_setprio(0);                                          \
        BARRIER;                                                                \
    } while (0)

    STAGE_A(0, 0, 0); STAGE_A(0, 1, 0);
    STAGE_B(0, 0, 0); STAGE_B(0, 1, 0);
    STAGE_A(1, 0, 1); STAGE_B(1, 0, 1);
    VMCNT4;
    BARRIER;

    for (int i = 0; i < 8; ++i) {
        const int tb  = 2 * i + 1;
        const int tc2 = (2 * i + 2) & 15;
        const int td  = (2 * i + 3) & 15;
        PH(0, 0, 0, 1, STAGE_A(1, 1, tb),  (void)0);
        PH(0, 0, 1, 0, STAGE_B(1, 1, tb),  (void)0);
        PH(0, 1, 0, 1, STAGE_A(0, 0, tc2), (void)0);
        PH(0, 1, 1, 0, STAGE_B(0, 0, tc2), VMCNT4);
        PH(1, 0, 0, 1, STAGE_A(0, 1, tc2), (void)0);
        PH(1, 0, 1, 0, STAGE_B(0, 1, tc2), (void)0);
        PH(1, 1, 0, 1, STAGE_A(1, 0, td),  (void)0);
        PH(1, 1, 1, 0, STAGE_B(1, 0, td),  VMCNT4);
    }

    VMCNT0;
    BARRIER;

    const int bat  = rowBase >> 11;
    const int tloc = rowBase & 2047;

    if (which < 2) {
        h16* dst = qk + (size_t)bat * 4194304 + (which == 1 ? 2097152u : 0u);
#pragma unroll
        for (int mh = 0; mh < 2; ++mh)
#pragma unroll
            for (int nh = 0; nh < 2; ++nh)
#pragma unroll
                for (int q = 0; q < 4; ++q)
#pragma unroll
                    for (int nf = 0; nf < 2; ++nf) {
                        int cc = nc0 + nh * 128 + wc * 32 + nf * 16 + fr;
#pragma unroll
                        for (int j = 0; j < 4; ++j) {
                            int rr = tloc + mh * 128 + wr * 64 + q * 16 + kq * 4 + j;
                            dst[(size_t)rr * 1024 + cc] = (h16)acc[mh][nh][q][nf][j];
                        }
                    }
    } else {
        h16* LT = (h16*)smem;  // [256 n][136 t-pad]
        const size_t bvt = (size_t)bat * 2097152;
#pragma unroll
        for (int mh = 0; mh < 2; ++mh) {
            __syncthreads();
#pragma unroll
            for (int nh = 0; nh < 2; ++nh)
#pragma unroll
                for (int q = 0; q < 4; ++q)
#pragma unroll
                    for (int nf = 0; nf < 2; ++nf) {
                        int cl = nh * 128 + wc * 32 + nf * 16 + fr;
#pragma unroll
                        for (int j = 0; j < 4; ++j) {
                            int rl = wr * 64 + q * 16 + kq * 4 + j;
                            LT[cl * 136 + rl] = (h16)acc[mh][nh][q][nf][j];
                        }
                    }
            __syncthreads();
#pragma unroll
            for (int p = 0; p < 8; ++p) {
                int idx = t + p * 512;
                int nl = idx >> 4;
                int tc = (idx & 15) * 8;
                *(f16x8*)&vt[bvt + (size_t)(nc0 + nl) * 2048 + tloc + mh * 128 + tc] =
                    *(f16x8*)&LT[nl * 136 + tc];
            }
        }
    }
#undef PH
#undef RD
#undef STAGE_A
#undef STAGE_B
#undef STAGE_OP
}

// ============ paired attention GEMM: S(g+1) blocks + O(g) blocks in one dispatch ====
// 128x128 tile, 4 waves, BK=32, T3-min double-buffered LDS (32 KiB),
// one barrier per K-step; next tile's global_load_lds issued before MFMA.
__global__ __launch_bounds__(256) void k_attn_pair(const h16* __restrict__ QKg,
                                                   float* __restrict__ Sbuf,
                                                   const h16* __restrict__ Pbuf,
                                                   const h16* __restrict__ Vtg,
                                                   float* __restrict__ Og,
                                                   int nS) {
    __shared__ char smem[32768];   // 2 bufs x (A 8KiB | B 8KiB)
    int bid = blockIdx.x;
    const int cpx = gridDim.x >> 3;               // grid always %8==0 (512/768/256)
    bid = (bid & 7) * cpx + (bid >> 3);           // bijective XCD swizzle

    const int t = threadIdx.x;
    const int lane = t & 63, wave = t >> 6;
    const int wr = wave >> 1, wc = wave & 1;
    const int fr = lane & 15, fk = (lane >> 4) * 8, fj = (lane >> 4) * 4;

    const h16 *A, *Bt;
    float* C;
    int K, lda, ldb, ldc, rowBase, colBase;
    if (bid < nS) {           // S = Q_sb @ K_sb^T  [2048x2048], K=1024
        int sb = bid >> 8, tile = bid & 255;
        rowBase = (tile >> 4) * 128; colBase = (tile & 15) * 128;
        A   = QKg + (size_t)sb * 4194304;
        Bt  = A + 2097152;
        C   = Sbuf + (size_t)sb * 4194304;
        K = 1024; lda = 1024; ldb = 1024; ldc = 2048;
    } else {                  // O = P_sb @ Vt_sb^T  [2048x1024], K=2048
        int ob = bid - nS;
        int sb = ob >> 7, tile = ob & 127;
        rowBase = (tile >> 3) * 128; colBase = (tile & 7) * 128;
        A   = Pbuf + (size_t)sb * 4194304;
        Bt  = Vtg + (size_t)sb * 2097152;
        C   = Og + (size_t)sb * 2097152;
        K = 2048; lda = 2048; ldb = 2048; ldc = 1024;
    }

    const int r0 = t >> 2, k00 = (t & 3) * 8;     // r1 = r0 + 64
    const h16* Ap0 = A + (size_t)(rowBase + r0) * lda + k00;
    const h16* Ap1 = A + (size_t)(rowBase + r0 + 64) * lda + k00;
    const h16* Bp0 = Bt + (size_t)(colBase + r0) * ldb + k00;
    const h16* Bp1 = Bt + (size_t)(colBase + r0 + 64) * ldb + k00;

#define STG2(BUF, KT) do {                                                    \
        char* _b = smem + (BUF) * 16384 + t * 16;                             \
        GLD16(Ap0 + (KT), _b);                                                \
        GLD16(Ap1 + (KT), _b + 4096);                                         \
        GLD16(Bp0 + (KT), _b + 8192);                                         \
        GLD16(Bp1 + (KT), _b + 12288);                                        \
    } while (0)

    f32x4 acc[4][4];
#pragma unroll
    for (int m = 0; m < 4; ++m)
#pragma unroll
        for (int n = 0; n < 4; ++n) acc[m][n] = (f32x4){0.f, 0.f, 0.f, 0.f};

#define MFMA_BUF(BUF) do {                                                    \
        const h16* lA = (const h16*)(smem + (BUF) * 16384);                   \
        const h16* lB = lA + 4096;                                            \
        f16x8 af[4], bf[4];                                                   \
        _Pragma("unroll") for (int m = 0; m < 4; ++m)                         \
            af[m] = *(const f16x8*)&lA[(wr * 64 + m * 16 + fr) * 32 + fk];    \
        _Pragma("unroll") for (int n = 0; n < 4; ++n)                         \
            bf[n] = *(const f16x8*)&lB[(wc * 64 + n * 16 + fr) * 32 + fk];    \
        _Pragma("unroll") for (int m = 0; m < 4; ++m)                         \
        _Pragma("unroll") for (int n = 0; n < 4; ++n)                         \
            acc[m][n] = __builtin_amdgcn_mfma_f32_16x16x32_f16(               \
                af[m], bf[n], acc[m][n], 0, 0, 0);                            \
    } while (0)

    STG2(0, 0);
    __syncthreads();           // drains vmcnt: buf0 ready
    int cur = 0;
    for (int kt = 32; kt < K; kt += 32) {
        STG2(cur ^ 1, kt);     // issue next tile's loads (targets other buf)
        MFMA_BUF(cur);         // compute current while loads fly
        __syncthreads();       // drain: next buf landed, all waves done w/ cur
        cur ^= 1;
    }
    MFMA_BUF(cur);             // last tile

#pragma unroll
    for (int m = 0; m < 4; ++m)
#pragma unroll
        for (int n = 0; n < 4; ++n) {
            int cc = colBase + wc * 64 + n * 16 + fr;
#pragma unroll
            for (int j = 0; j < 4; ++j) {
                int rr = rowBase + wr * 64 + m * 16 + fj + j;
                C[(size_t)rr * ldc + cc] = acc[m][n][j];
            }
        }
#undef STG2
#undef MFMA_BUF
}

// ---------------- row softmax over group: S fp32 [rows][2048] -> P fp16 ----------------
__global__ __launch_bounds__(256) void k_softmax(const float* __restrict__ S,
                                                 h16* __restrict__ P) {
    int row = blockIdx.x, t = threadIdx.x;
    const float* sr = S + (size_t)row * 2048 + t * 8;
    f32x4 a = *(const f32x4*)sr;
    f32x4 b = *(const f32x4*)(sr + 4);
    float m = fmaxf(fmaxf(fmaxf(a[0], a[1]), fmaxf(a[2], a[3])),
                    fmaxf(fmaxf(b[0], b[1]), fmaxf(b[2], b[3])));
#pragma unroll
    for (int off = 32; off; off >>= 1) m = fmaxf(m, __shfl_xor(m, off));
    __shared__ float redm[4], reds[4];
    if ((t & 63) == 0) redm[t >> 6] = m;
    __syncthreads();
    m = fmaxf(fmaxf(redm[0], redm[1]), fmaxf(redm[2], redm[3]));

    float e[8];
    e[0] = __expf(a[0] - m); e[1] = __expf(a[1] - m);
    e[2] = __expf(a[2] - m); e[3] = __expf(a[3] - m);
    e[4] = __expf(b[0] - m); e[5] = __expf(b[1] - m);
    e[6] = __expf(b[2] - m); e[7] = __expf(b[3] - m);
    float s = ((e[0] + e[1]) + (e[2] + e[3])) + ((e[4] + e[5]) + (e[6] + e[7]));
#pragma unroll
    for (int off = 32; off; off >>= 1) s += __shfl_xor(s, off);
    if ((t & 63) == 0) reds[t >> 6] = s;
    __syncthreads();
    s = (reds[0] + reds[1]) + (reds[2] + reds[3]);
    float inv = 1.0f / s;
    f16x8 o;
#pragma unroll
    for (int i = 0; i < 8; ++i) o[i] = (h16)(e[i] * inv);
    *(f16x8*)(P + (size_t)row * 2048 + t * 8) = o;
}

extern "C" void kernel_launch(void* const* d_in, const int* in_sizes, int n_in,
                              void* d_out, int out_size, void* d_ws, size_t ws_size,
                              hipStream_t stream) {
    (void)in_sizes; (void)n_in; (void)out_size; (void)ws_size;
    const float* X  = (const float*)d_in[0];
    const float* Wq = (const float*)d_in[1];
    const float* Wk = (const float*)d_in[2];
    const float* Wv = (const float*)d_in[3];

    char* ws = (char*)d_ws;
    h16*   Xh = (h16*)ws;
    h16*   Wt = (h16*)(ws + 33554432);
    h16*   Vt = (h16*)(ws + 39845888);
    float* S  = (float*)ws;               // reuses dead Xh region (group of 2)
    h16*   P  = (h16*)(ws + 73400320);    // group of 2
    h16*   QK = (h16*)d_out;
    float* O  = (float*)d_out;

    hipFuncSetAttribute((const void*)k_gemm_qkv256,
                        hipFuncAttributeMaxDynamicSharedMemorySize, 131072);

    k_convX<<<8192, 256, 0, stream>>>(X, Xh);
    k_convW<<<768, 256, 0, stream>>>(Wq, Wk, Wv, Wt);
    k_gemm_qkv256<<<768, 512, 131072, stream>>>(Xh, Wt, QK, Vt);

    const size_t QKstride = 2 * 4194304;  // 2 batches of [Q|K]
    const size_t Vstride  = 2 * 2097152;

    // S(0)
    k_attn_pair<<<512, 256, 0, stream>>>(QK, S, P, Vt, O, 512);
    k_softmax<<<4096, 256, 0, stream>>>(S, P);
    // pairs: S(g) + O(g-1)
    for (int g = 1; g < 4; ++g) {
        k_attn_pair<<<768, 256, 0, stream>>>(
            QK + (size_t)g * QKstride, S,
            P, Vt + (size_t)(g - 1) * Vstride, O + (size_t)(g - 1) * Vstride, 512);
        k_softmax<<<4096, 256, 0, stream>>>(S, P);
    }
    // O(3)
    k_attn_pair<<<256, 256, 0, stream>>>(
        QK, S, P, Vt + 3 * Vstride, O + 3 * Vstride, 0);
}

// Round 8
// 398.231 us; speedup vs baseline: 2.0041x; 1.0428x over previous
//
#include <hip/hip_runtime.h>
#include <stdint.h>

typedef _Float16 h16;
typedef __attribute__((ext_vector_type(8))) _Float16 f16x8;
typedef __attribute__((ext_vector_type(4))) float f32x4;

// Problem: B=8, T=2048, D=1024, NODES=1024  (fp32 in/out)
// ws layout (bytes):
//   Xh  @ 0         : 33554432   (X fp16)          -- dead after qkv GEMM
//   Wt  @ 33554432  : 6291456    (W^T fp16 [n][d]) -- dead after qkv GEMM
//   Vt  @ 39845888  : 33554432   (V^T fp16 [b][n][t]) -- live to end
//   S   @ 0         : 33554432   (group of 2 batches, fp32; reuses Xh)
//   P   @ 73400320  : 16777216   (group of 2 batches, fp16)
// Q,K fp16 live in d_out: per-batch 8 MiB chunk [Q_b | K_b]; batch b's fp32
// output exactly overwrites [Q_b|K_b] after its S GEMM consumed them.
// Launch chain: S0, SM0, [S1+O0], SM1, [S2+O1], SM2, [S3+O2], SM3, O3.

#define GLD16(gsrc, ldst)                                                     \
    __builtin_amdgcn_global_load_lds(                                         \
        (const __attribute__((address_space(1))) uint32_t*)(gsrc),            \
        (__attribute__((address_space(3))) uint32_t*)(ldst), 16, 0, 0)

#define FENCE asm volatile("" ::: "memory")
#define BARRIER do { FENCE; __builtin_amdgcn_s_barrier(); FENCE; } while (0)
#define LGKM0  asm volatile("s_waitcnt lgkmcnt(0)" ::: "memory")
#define VMCNT4 asm volatile("s_waitcnt vmcnt(4)" ::: "memory")
#define VMCNT0 asm volatile("s_waitcnt vmcnt(0)" ::: "memory")

// ---------------- convert X fp32 -> fp16 ----------------
__global__ __launch_bounds__(256) void k_convX(const float* __restrict__ X,
                                               h16* __restrict__ Xh) {
    size_t i = ((size_t)blockIdx.x * 256 + threadIdx.x) * 8;
    f32x4 a = *(const f32x4*)(X + i);
    f32x4 b = *(const f32x4*)(X + i + 4);
    f16x8 o;
    o[0] = (h16)a[0]; o[1] = (h16)a[1]; o[2] = (h16)a[2]; o[3] = (h16)a[3];
    o[4] = (h16)b[0]; o[5] = (h16)b[1]; o[6] = (h16)b[2]; o[7] = (h16)b[3];
    *(f16x8*)(Xh + i) = o;
}

// ---------------- transpose+convert W [d][n] fp32 -> Wt [n][d] fp16 ----------------
__global__ __launch_bounds__(256) void k_convW(const float* __restrict__ W0,
                                               const float* __restrict__ W1,
                                               const float* __restrict__ W2,
                                               h16* __restrict__ Wt) {
    __shared__ h16 LT[64 * 72];
    int which = blockIdx.x >> 8;
    int tile  = blockIdx.x & 255;
    int d0 = (tile >> 4) * 64, n0 = (tile & 15) * 64;
    const float* W = (which == 0) ? W0 : ((which == 1) ? W1 : W2);
    h16* dst = Wt + (size_t)which * (1024 * 1024);
    int t = threadIdx.x;
#pragma unroll
    for (int p = 0; p < 4; ++p) {
        int c = t + p * 256;
        int r = c >> 4;
        int cf = (c & 15) * 4;
        f32x4 v = *(const f32x4*)&W[(size_t)(d0 + r) * 1024 + n0 + cf];
#pragma unroll
        for (int e = 0; e < 4; ++e) LT[(cf + e) * 72 + r] = (h16)v[e];
    }
    __syncthreads();
#pragma unroll
    for (int p = 0; p < 2; ++p) {
        int q = t + p * 256;
        int nl = q >> 3;
        int dc = (q & 7) * 8;
        f16x8 v = *(f16x8*)&LT[nl * 72 + dc];
        *(f16x8*)&dst[(size_t)(n0 + nl) * 1024 + d0 + dc] = v;
    }
}

// ============ 256x256 8-phase QKV GEMM (T2+T3+T4+T5) — unchanged from r5 ============
__global__ __launch_bounds__(512, 2) void k_gemm_qkv256(const h16* __restrict__ Xh,
                                                        const h16* __restrict__ Wt,
                                                        h16* __restrict__ qk,
                                                        h16* __restrict__ vt) {
    extern __shared__ char smem[];
    const int t = threadIdx.x;
    const int lane = t & 63, wave = t >> 6;
    const int wr = wave >> 2, wc = wave & 3;
    const int fr = lane & 15, kq = lane >> 4;
    const int sw = fr & 7;
    const int loff = (((t & 7) ^ ((t >> 3) & 7)) * 8);

    int bid = blockIdx.x;
    bid = (bid & 7) * 96 + (bid >> 3);        // XCD swizzle (768 % 8 == 0)
    const int nt = bid % 12, mt = bid / 12;
    const int rowBase = mt * 256;
    const int colBaseF = nt * 256;
    const int which = nt >> 2;
    const int nc0 = colBaseF & 1023;
    const h16* A  = Xh;
    const h16* Bt = Wt + (size_t)which * (1024 * 1024);

#define STAGE_OP(OPREG, OPPTR, OPROW, BUF, H, KT) do {                          \
        const h16* _src = (OPPTR) + (size_t)((OPROW) + (H) * 128 + (t >> 3)) * 1024 \
                          + (KT) * 64 + loff;                                   \
        char* _dst = smem + (OPREG) + (BUF) * 32768 + (H) * 16384 + t * 16;     \
        GLD16(_src, _dst);                                                      \
        GLD16(_src + 64 * 1024, _dst + 8192);                                   \
    } while (0)
#define STAGE_A(BUF, H, KT) STAGE_OP(0, A, rowBase, BUF, H, KT)
#define STAGE_B(BUF, H, KT) STAGE_OP(65536, Bt, nc0, BUF, H, KT)

#define RD(REG, ROW, SLOT) \
    (*(const f16x8*)(smem + (REG) + (ROW) * 128 + ((((SLOT)) ^ sw) << 4)))

    f32x4 acc[2][2][4][2];
#pragma unroll
    for (int mh = 0; mh < 2; ++mh)
#pragma unroll
        for (int nh = 0; nh < 2; ++nh)
#pragma unroll
            for (int q = 0; q < 4; ++q)
#pragma unroll
                for (int nf = 0; nf < 2; ++nf)
                    acc[mh][nh][q][nf] = (f32x4){0.f, 0.f, 0.f, 0.f};

    f16x8 a[4][2], b[2][2];

#define PH(BUF, MH, NH, DOA, STG, VM) do {                                      \
        if (DOA) {                                                              \
            _Pragma("unroll") for (int q = 0; q < 4; ++q)                       \
            _Pragma("unroll") for (int ks = 0; ks < 2; ++ks)                    \
                a[q][ks] = RD((BUF) * 32768,                                    \
                              (MH) * 128 + wr * 64 + q * 16 + fr, kq + ks * 4); \
        }                                                                       \
        _Pragma("unroll") for (int nf = 0; nf < 2; ++nf)                        \
        _Pragma("unroll") for (int ks = 0; ks < 2; ++ks)                        \
            b[nf][ks] = RD(65536 + (BUF) * 32768,                               \
                           (NH) * 128 + wc * 32 + nf * 16 + fr, kq + ks * 4);   \
        STG;                                                                    \
        VM;                                                                     \
        BARRIER; LGKM0;                                                         \
        __builtin_amdgcn_s_setprio(1);                                          \
        _Pragma("unroll") for (int q = 0; q < 4; ++q)                           \
        _Pragma("unroll") for (int nf = 0; nf < 2; ++nf)                        \
        _Pragma("unroll") for (int ks = 0; ks < 2; ++ks)                        \
            acc[MH][NH][q][nf] = __builtin_amdgcn_mfma_f32_16x16x32_f16(        \
                a[q][ks], b[nf][ks], acc[MH][NH][q][nf], 0, 0, 0);              \
        __builtin_amdgcn_s_setprio(0);                                          \
        BARRIER;                                                                \
    } while (0)

    STAGE_A(0, 0, 0); STAGE_A(0, 1, 0);
    STAGE_B(0, 0, 0); STAGE_B(0, 1, 0);
    STAGE_A(1, 0, 1); STAGE_B(1, 0, 1);
    VMCNT4;
    BARRIER;

    for (int i = 0; i < 8; ++i) {
        const int tb  = 2 * i + 1;
        const int tc2 = (2 * i + 2) & 15;
        const int td  = (2 * i + 3) & 15;
        PH(0, 0, 0, 1, STAGE_A(1, 1, tb),  (void)0);
        PH(0, 0, 1, 0, STAGE_B(1, 1, tb),  (void)0);
        PH(0, 1, 0, 1, STAGE_A(0, 0, tc2), (void)0);
        PH(0, 1, 1, 0, STAGE_B(0, 0, tc2), VMCNT4);
        PH(1, 0, 0, 1, STAGE_A(0, 1, tc2), (void)0);
        PH(1, 0, 1, 0, STAGE_B(0, 1, tc2), (void)0);
        PH(1, 1, 0, 1, STAGE_A(1, 0, td),  (void)0);
        PH(1, 1, 1, 0, STAGE_B(1, 0, td),  VMCNT4);
    }

    VMCNT0;
    BARRIER;

    const int bat  = rowBase >> 11;
    const int tloc = rowBase & 2047;

    if (which < 2) {
        h16* dst = qk + (size_t)bat * 4194304 + (which == 1 ? 2097152u : 0u);
#pragma unroll
        for (int mh = 0; mh < 2; ++mh)
#pragma unroll
            for (int nh = 0; nh < 2; ++nh)
#pragma unroll
                for (int q = 0; q < 4; ++q)
#pragma unroll
                    for (int nf = 0; nf < 2; ++nf) {
                        int cc = nc0 + nh * 128 + wc * 32 + nf * 16 + fr;
#pragma unroll
                        for (int j = 0; j < 4; ++j) {
                            int rr = tloc + mh * 128 + wr * 64 + q * 16 + kq * 4 + j;
                            dst[(size_t)rr * 1024 + cc] = (h16)acc[mh][nh][q][nf][j];
                        }
                    }
    } else {
        h16* LT = (h16*)smem;  // [256 n][136 t-pad]
        const size_t bvt = (size_t)bat * 2097152;
#pragma unroll
        for (int mh = 0; mh < 2; ++mh) {
            __syncthreads();
#pragma unroll
            for (int nh = 0; nh < 2; ++nh)
#pragma unroll
                for (int q = 0; q < 4; ++q)
#pragma unroll
                    for (int nf = 0; nf < 2; ++nf) {
                        int cl = nh * 128 + wc * 32 + nf * 16 + fr;
#pragma unroll
                        for (int j = 0; j < 4; ++j) {
                            int rl = wr * 64 + q * 16 + kq * 4 + j;
                            LT[cl * 136 + rl] = (h16)acc[mh][nh][q][nf][j];
                        }
                    }
            __syncthreads();
#pragma unroll
            for (int p = 0; p < 8; ++p) {
                int idx = t + p * 512;
                int nl = idx >> 4;
                int tc = (idx & 15) * 8;
                *(f16x8*)&vt[bvt + (size_t)(nc0 + nl) * 2048 + tloc + mh * 128 + tc] =
                    *(f16x8*)&LT[nl * 136 + tc];
            }
        }
    }
#undef PH
#undef RD
#undef STAGE_A
#undef STAGE_B
#undef STAGE_OP
}

// ============ paired attention GEMM: S(g+1) blocks + O(g) blocks in one dispatch ====
// 128x128 tile, 4 waves, BK=64, 2-phase double-buffered LDS (64 KiB),
// both-sides XOR swizzle (inverse-swizzled global src, swizzled ds_read).
__global__ __launch_bounds__(256) void k_attn_pair(const h16* __restrict__ QKg,
                                                   float* __restrict__ Sbuf,
                                                   const h16* __restrict__ Pbuf,
                                                   const h16* __restrict__ Vtg,
                                                   float* __restrict__ Og,
                                                   int nS) {
    extern __shared__ char smem[];  // 2 bufs x (A 16KiB | B 16KiB) = 64 KiB
    int bid = blockIdx.x;
    const int cpx = gridDim.x >> 3;               // grid always %8==0 (512/768/256)
    bid = (bid & 7) * cpx + (bid >> 3);           // bijective XCD swizzle

    const int t = threadIdx.x;
    const int lane = t & 63, wave = t >> 6;
    const int wr = wave >> 1, wc = wave & 1;
    const int fr = lane & 15, kq = lane >> 4, fj = (lane >> 4) * 4;
    const int sw = fr & 7;
    const int loff = (((t & 7) ^ ((t >> 3) & 7)) * 8);  // inverse-swizzle (halves)

    const h16 *A, *Bt;
    float* C;
    int K, lda, ldb, ldc, rowBase, colBase;
    if (bid < nS) {           // S = Q_sb @ K_sb^T  [2048x2048], K=1024
        int sb = bid >> 8, tile = bid & 255;
        rowBase = (tile >> 4) * 128; colBase = (tile & 15) * 128;
        A   = QKg + (size_t)sb * 4194304;
        Bt  = A + 2097152;
        C   = Sbuf + (size_t)sb * 4194304;
        K = 1024; lda = 1024; ldb = 1024; ldc = 2048;
    } else {                  // O = P_sb @ Vt_sb^T  [2048x1024], K=2048
        int ob = bid - nS;
        int sb = ob >> 7, tile = ob & 127;
        rowBase = (tile >> 3) * 128; colBase = (tile & 7) * 128;
        A   = Pbuf + (size_t)sb * 4194304;
        Bt  = Vtg + (size_t)sb * 2097152;
        C   = Og + (size_t)sb * 2097152;
        K = 2048; lda = 2048; ldb = 2048; ldc = 1024;
    }

    // Staging: tile 128 rows x 64 halves (128B/row, 8 slots of 16B).
    // Thread t, part p: row = (t>>3) + p*32, physical slot = t&7,
    // global k-offset = loff (logical slot = (t&7)^(row&7), row&7 == (t>>3)&7).
    const h16* Asrc = A + (size_t)(rowBase + (t >> 3)) * lda + loff;
    const h16* Bsrc = Bt + (size_t)(colBase + (t >> 3)) * ldb + loff;
    const size_t a32 = (size_t)32 * lda, b32 = (size_t)32 * ldb;

#define STG2(BUF, KT) do {                                                    \
        char* _ba = smem + (BUF) * 32768 + t * 16;                            \
        char* _bb = _ba + 16384;                                              \
        GLD16(Asrc + (KT), _ba);                                              \
        GLD16(Asrc + (KT) + a32, _ba + 4096);                                 \
        GLD16(Asrc + (KT) + 2 * a32, _ba + 8192);                             \
        GLD16(Asrc + (KT) + 3 * a32, _ba + 12288);                            \
        GLD16(Bsrc + (KT), _bb);                                              \
        GLD16(Bsrc + (KT) + b32, _bb + 4096);                                 \
        GLD16(Bsrc + (KT) + 2 * b32, _bb + 8192);                             \
        GLD16(Bsrc + (KT) + 3 * b32, _bb + 12288);                            \
    } while (0)

    f32x4 acc[4][4];
#pragma unroll
    for (int m = 0; m < 4; ++m)
#pragma unroll
        for (int n = 0; n < 4; ++n) acc[m][n] = (f32x4){0.f, 0.f, 0.f, 0.f};

    // swizzled fragment read: row r, logical slot s -> byte r*128 + ((s^(r&7))*16)
#define RDF(BASE, R, S) \
    (*(const f16x8*)(smem + (BASE) + (R) * 128 + (((S) ^ sw) << 4)))

#define MFMA_BUF(BUF) do {                                                    \
        f16x8 af[4][2], bf[4][2];                                             \
        _Pragma("unroll") for (int m = 0; m < 4; ++m)                         \
        _Pragma("unroll") for (int ks = 0; ks < 2; ++ks)                      \
            af[m][ks] = RDF((BUF) * 32768,                                    \
                            wr * 64 + m * 16 + fr, kq + ks * 4);              \
        _Pragma("unroll") for (int n = 0; n < 4; ++n)                         \
        _Pragma("unroll") for (int ks = 0; ks < 2; ++ks)                      \
            bf[n][ks] = RDF((BUF) * 32768 + 16384,                            \
                            wc * 64 + n * 16 + fr, kq + ks * 4);              \
        _Pragma("unroll") for (int m = 0; m < 4; ++m)                         \
        _Pragma("unroll") for (int n = 0; n < 4; ++n)                         \
        _Pragma("unroll") for (int ks = 0; ks < 2; ++ks)                      \
            acc[m][n] = __builtin_amdgcn_mfma_f32_16x16x32_f16(               \
                af[m][ks], bf[n][ks], acc[m][n], 0, 0, 0);                    \
    } while (0)

    STG2(0, 0);
    __syncthreads();           // drains vmcnt: buf0 ready
    int cur = 0;
    for (int kt = 64; kt < K; kt += 64) {
        STG2(cur ^ 1, kt);     // issue next tile's loads (other buf)
        MFMA_BUF(cur);         // compute current while loads fly
        __syncthreads();       // drain: next buf landed, all waves done w/ cur
        cur ^= 1;
    }
    MFMA_BUF(cur);             // last tile

#pragma unroll
    for (int m = 0; m < 4; ++m)
#pragma unroll
        for (int n = 0; n < 4; ++n) {
            int cc = colBase + wc * 64 + n * 16 + fr;
#pragma unroll
            for (int j = 0; j < 4; ++j) {
                int rr = rowBase + wr * 64 + m * 16 + fj + j;
                C[(size_t)rr * ldc + cc] = acc[m][n][j];
            }
        }
#undef STG2
#undef RDF
#undef MFMA_BUF
}

// ---------------- row softmax over group: S fp32 [rows][2048] -> P fp16 ----------------
__global__ __launch_bounds__(256) void k_softmax(const float* __restrict__ S,
                                                 h16* __restrict__ P) {
    int row = blockIdx.x, t = threadIdx.x;
    const float* sr = S + (size_t)row * 2048 + t * 8;
    f32x4 a = *(const f32x4*)sr;
    f32x4 b = *(const f32x4*)(sr + 4);
    float m = fmaxf(fmaxf(fmaxf(a[0], a[1]), fmaxf(a[2], a[3])),
                    fmaxf(fmaxf(b[0], b[1]), fmaxf(b[2], b[3])));
#pragma unroll
    for (int off = 32; off; off >>= 1) m = fmaxf(m, __shfl_xor(m, off));
    __shared__ float redm[4], reds[4];
    if ((t & 63) == 0) redm[t >> 6] = m;
    __syncthreads();
    m = fmaxf(fmaxf(redm[0], redm[1]), fmaxf(redm[2], redm[3]));

    float e[8];
    e[0] = __expf(a[0] - m); e[1] = __expf(a[1] - m);
    e[2] = __expf(a[2] - m); e[3] = __expf(a[3] - m);
    e[4] = __expf(b[0] - m); e[5] = __expf(b[1] - m);
    e[6] = __expf(b[2] - m); e[7] = __expf(b[3] - m);
    float s = ((e[0] + e[1]) + (e[2] + e[3])) + ((e[4] + e[5]) + (e[6] + e[7]));
#pragma unroll
    for (int off = 32; off; off >>= 1) s += __shfl_xor(s, off);
    if ((t & 63) == 0) reds[t >> 6] = s;
    __syncthreads();
    s = (reds[0] + reds[1]) + (reds[2] + reds[3]);
    float inv = 1.0f / s;
    f16x8 o;
#pragma unroll
    for (int i = 0; i < 8; ++i) o[i] = (h16)(e[i] * inv);
    *(f16x8*)(P + (size_t)row * 2048 + t * 8) = o;
}

extern "C" void kernel_launch(void* const* d_in, const int* in_sizes, int n_in,
                              void* d_out, int out_size, void* d_ws, size_t ws_size,
                              hipStream_t stream) {
    (void)in_sizes; (void)n_in; (void)out_size; (void)ws_size;
    const float* X  = (const float*)d_in[0];
    const float* Wq = (const float*)d_in[1];
    const float* Wk = (const float*)d_in[2];
    const float* Wv = (const float*)d_in[3];

    char* ws = (char*)d_ws;
    h16*   Xh = (h16*)ws;
    h16*   Wt = (h16*)(ws + 33554432);
    h16*   Vt = (h16*)(ws + 39845888);
    float* S  = (float*)ws;               // reuses dead Xh region (group of 2)
    h16*   P  = (h16*)(ws + 73400320);    // group of 2
    h16*   QK = (h16*)d_out;
    float* O  = (float*)d_out;

    hipFuncSetAttribute((const void*)k_gemm_qkv256,
                        hipFuncAttributeMaxDynamicSharedMemorySize, 131072);
    hipFuncSetAttribute((const void*)k_attn_pair,
                        hipFuncAttributeMaxDynamicSharedMemorySize, 65536);

    k_convX<<<8192, 256, 0, stream>>>(X, Xh);
    k_convW<<<768, 256, 0, stream>>>(Wq, Wk, Wv, Wt);
    k_gemm_qkv256<<<768, 512, 131072, stream>>>(Xh, Wt, QK, Vt);

    const size_t QKstride = 2 * 4194304;  // 2 batches of [Q|K]
    const size_t Vstride  = 2 * 2097152;

    // S(0)
    k_attn_pair<<<512, 256, 65536, stream>>>(QK, S, P, Vt, O, 512);
    k_softmax<<<4096, 256, 0, stream>>>(S, P);
    // pairs: S(g) + O(g-1)
    for (int g = 1; g < 4; ++g) {
        k_attn_pair<<<768, 256, 65536, stream>>>(
            QK + (size_t)g * QKstride, S,
            P, Vt + (size_t)(g - 1) * Vstride, O + (size_t)(g - 1) * Vstride, 512);
        k_softmax<<<4096, 256, 0, stream>>>(S, P);
    }
    // O(3)
    k_attn_pair<<<256, 256, 65536, stream>>>(
        QK, S, P, Vt + 3 * Vstride, O + 3 * Vstride, 0);
}